// Round 1
// baseline (70.711 us; speedup 1.0000x reference)
//
#include <hip/hip_runtime.h>

// se_invariant_net: the reference LayerNorm is over a size-1 feature axis,
// so (h-mean)*rsqrt(var+eps)*scale + offset == offset exactly — the output
// is independent of x. Whole net collapses to:
//   h1 = relu(offset*w1 + b1); h2 = relu(h1@w2 + b2); v = h2@wf + bf
//   out[b,i,:] = N * v   (sum over N identical rows)
// B=2, N=1024, H=64, N_VALS=3 -> out_size = 6144 floats.

#define H 64
#define NVALS 3
#define NSUM 1024.0f   // N, the summed axis length

__global__ void se_invariant_net_19774029431055_kernel(
    const float* __restrict__ ln_offset,
    const float* __restrict__ w1, const float* __restrict__ b1,
    const float* __restrict__ w2, const float* __restrict__ b2,
    const float* __restrict__ wf, const float* __restrict__ bf,
    float* __restrict__ out, int total)
{
    __shared__ float h1[H];
    __shared__ float h2[H];
    __shared__ float res[NVALS];

    const int t = threadIdx.x;

    // h1 = relu(offset * w1 + b1)   (w1 is [1,H] flat)
    if (t < H) {
        float v = ln_offset[0] * w1[t] + b1[t];
        h1[t] = v > 0.0f ? v : 0.0f;
    }
    __syncthreads();

    // h2 = relu(h1 @ w2 + b2)       (w2 is [H,H] row-major: w2[j,k] = w2[j*H+k])
    if (t < H) {
        float acc = b2[t];
        #pragma unroll
        for (int j = 0; j < H; ++j) acc += h1[j] * w2[j * H + t];
        h2[t] = acc > 0.0f ? acc : 0.0f;
    }
    __syncthreads();

    // v = h2 @ wf + bf, scaled by N  (wf is [H,NVALS]: wf[k,v] = wf[k*NVALS+v])
    if (t < NVALS) {
        float acc = bf[t];
        #pragma unroll
        for (int k = 0; k < H; ++k) acc += h2[k] * wf[k * NVALS + t];
        res[t] = acc * NSUM;
    }
    __syncthreads();

    // Broadcast: out[b,i,v] = res[v]; flat index % NVALS == v.
    const int idx = blockIdx.x * blockDim.x + t;
    if (idx < total) out[idx] = res[idx % NVALS];
}

extern "C" void kernel_launch(void* const* d_in, const int* in_sizes, int n_in,
                              void* d_out, int out_size, void* d_ws, size_t ws_size,
                              hipStream_t stream)
{
    // setup_inputs order: x, ln_scale, ln_offset, w1, b1, w2, b2, wf, bf
    const float* ln_offset = (const float*)d_in[2];
    const float* w1 = (const float*)d_in[3];
    const float* b1 = (const float*)d_in[4];
    const float* w2 = (const float*)d_in[5];
    const float* b2 = (const float*)d_in[6];
    const float* wf = (const float*)d_in[7];
    const float* bf = (const float*)d_in[8];
    float* out = (float*)d_out;

    const int block = 256;
    const int grid = (out_size + block - 1) / block;  // 6144/256 = 24 blocks
    se_invariant_net_19774029431055_kernel<<<grid, block, 0, stream>>>(
        ln_offset, w1, b1, w2, b2, wf, bf, out, out_size);
}